// Round 1
// baseline (399.121 us; speedup 1.0000x reference)
//
#include <hip/hip_runtime.h>
#include <stdint.h>

#define WINDOW 2048
#define EMBED  1024
#define BATCH  8
#define MTOT   (BATCH*WINDOW)   // 16384 rows total

typedef unsigned short u16;
typedef __bf16 bf16x8 __attribute__((ext_vector_type(8)));
typedef float  f32x4  __attribute__((ext_vector_type(4)));

#define BM 128
#define BN 128
#define BK 64
#define KSCALE 0.04508422717564447f   /* log2(e)/32 : folded into stored K so exp(x)=exp2(S) */

__device__ __forceinline__ u16 f2bf(float f) {
  union { float f; unsigned u; } a; a.f = f;
  unsigned r = a.u + 0x7FFF + ((a.u >> 16) & 1);   // RNE
  return (u16)(r >> 16);
}
__device__ __forceinline__ float bf2f(u16 u) {
  union { unsigned u; float f; } a; a.u = ((unsigned)u) << 16;
  return a.f;
}

__device__ __forceinline__ void gload16(const u16* g, u16* l) {
  __builtin_amdgcn_global_load_lds(
      (const __attribute__((address_space(1))) unsigned int*)g,
      (__attribute__((address_space(3))) unsigned int*)l, 16, 0, 0);
}

// acc[4][4] += A[128 x klen] * B[128 x klen]^T   (bf16 in, fp32 out)
// A,B row-major bf16; klen multiple of 64. 256 threads = 4 waves in 2x2.
__device__ __forceinline__ void gemm_core(
    const u16* __restrict__ A, int lda,
    const u16* __restrict__ B, int ldb,
    int klen, u16* As, u16* Bs, f32x4 acc[4][4])
{
  const int t    = threadIdx.x;
  const int lane = t & 63;
  const int wr   = ((t >> 6) >> 1) * 64;
  const int wc   = ((t >> 6) & 1) * 64;
  const int lrow = lane & 15;
  const int lko  = (lane >> 4) * 8;

  for (int kt = 0; kt < klen; kt += BK) {
    #pragma unroll
    for (int l2 = 0; l2 < 4; ++l2) {
      int f   = l2 * 256 + t;          // 16B chunk index, linear in LDS (wave-uniform base + lane*16)
      int row = f >> 3;
      int cc  = (f & 7) * 8;
      gload16(A + (size_t)row * lda + kt + cc, As + f * 8);
      gload16(B + (size_t)row * ldb + kt + cc, Bs + f * 8);
    }
    __syncthreads();
    #pragma unroll
    for (int kk = 0; kk < 2; ++kk) {
      bf16x8 av[4], bv[4];
      const int ko = kk * 32 + lko;
      #pragma unroll
      for (int mi = 0; mi < 4; ++mi)
        av[mi] = *(const bf16x8*)(As + (wr + mi * 16 + lrow) * BK + ko);
      #pragma unroll
      for (int ni = 0; ni < 4; ++ni)
        bv[ni] = *(const bf16x8*)(Bs + (wc + ni * 16 + lrow) * BK + ko);
      #pragma unroll
      for (int mi = 0; mi < 4; ++mi)
        #pragma unroll
        for (int ni = 0; ni < 4; ++ni)
          acc[mi][ni] = __builtin_amdgcn_mfma_f32_16x16x32_bf16(av[mi], bv[ni], acc[mi][ni], 0, 0, 0);
    }
    __syncthreads();
  }
}

__device__ __forceinline__ void zero_acc(f32x4 acc[4][4]) {
  const f32x4 z = {0.f, 0.f, 0.f, 0.f};
  #pragma unroll
  for (int i = 0; i < 4; ++i)
    #pragma unroll
    for (int j = 0; j < 4; ++j) acc[i][j] = z;
}

// ---------------- fp32 -> bf16 convert (vectorized) ----------------
__global__ __launch_bounds__(256) void k_cvt(const float* __restrict__ in,
                                             u16* __restrict__ out, int n) {
  int i = (blockIdx.x * 256 + threadIdx.x) * 4;
  if (i >= n) return;
  float4 v = *(const float4*)(in + i);
  ushort4 o;
  o.x = f2bf(v.x); o.y = f2bf(v.y); o.z = f2bf(v.z); o.w = f2bf(v.w);
  *(ushort4*)(out + i) = o;
}

// ---------------- QKV projection: C = X * W^T + b ----------------
__global__ __launch_bounds__(256) void k_qkv(
    const u16* __restrict__ Xb, const u16* __restrict__ Wb,
    const float* __restrict__ bq, const float* __restrict__ bk, const float* __restrict__ bv,
    u16* __restrict__ Q, u16* __restrict__ Ks, u16* __restrict__ V)
{
  __shared__ u16 As[BM*BK], Bs[BN*BK];
  const int m0 = blockIdx.x * BM;
  const int n0 = blockIdx.y * BN;
  const int z  = blockIdx.z;
  const u16*  W    = Wb + (size_t)z * EMBED * EMBED;
  const float* bias = (z == 0) ? bq : (z == 1) ? bk : bv;
  u16* out          = (z == 0) ? Q  : (z == 1) ? Ks : V;
  const float scale = (z == 1) ? KSCALE : 1.0f;

  f32x4 acc[4][4]; zero_acc(acc);
  gemm_core(Xb + (size_t)m0 * EMBED, EMBED, W + (size_t)n0 * EMBED, EMBED,
            EMBED, As, Bs, acc);

  const int lane = threadIdx.x & 63, w = threadIdx.x >> 6;
  const int wr = (w >> 1) * 64, wc = (w & 1) * 64;
  #pragma unroll
  for (int mi = 0; mi < 4; ++mi)
    #pragma unroll
    for (int ni = 0; ni < 4; ++ni)
      #pragma unroll
      for (int r = 0; r < 4; ++r) {
        int gm = m0 + wr + mi * 16 + (lane >> 4) * 4 + r;
        int gn = n0 + wc + ni * 16 + (lane & 15);
        out[(size_t)gm * EMBED + gn] = f2bf((acc[mi][ni][r] + bias[gn]) * scale);
      }
}

// ---------------- S = Q*K^T, P = exp2(S) masked, D[j] += colsum ----------------
__global__ __launch_bounds__(256) void k_spd(
    const u16* __restrict__ Q, const u16* __restrict__ Ks,
    u16* __restrict__ P, float* __restrict__ D)
{
  const int i0 = blockIdx.x * BM;
  const int j0 = blockIdx.y * BN;
  if (j0 > i0) return;                       // fully-masked tile: P never read there
  const int b  = blockIdx.z;
  __shared__ u16 As[BM*BK], Bs[BN*BK];
  const u16* A = Q  + (size_t)b * WINDOW * EMBED + (size_t)i0 * EMBED;
  const u16* B = Ks + (size_t)b * WINDOW * EMBED + (size_t)j0 * EMBED;
  f32x4 acc[4][4]; zero_acc(acc);
  gemm_core(A, EMBED, B, EMBED, EMBED, As, Bs, acc);

  u16* Pb = P + (size_t)b * WINDOW * WINDOW;
  float* Db = D + (size_t)b * WINDOW;
  const int lane = threadIdx.x & 63, w = threadIdx.x >> 6;
  const int wr = (w >> 1) * 64, wc = (w & 1) * 64;
  #pragma unroll
  for (int ni = 0; ni < 4; ++ni) {
    int gj = j0 + wc + ni * 16 + (lane & 15);
    float csum = 0.f;
    #pragma unroll
    for (int mi = 0; mi < 4; ++mi)
      #pragma unroll
      for (int r = 0; r < 4; ++r) {
        int gi = i0 + wr + mi * 16 + (lane >> 4) * 4 + r;
        float p = (gi >= gj) ? exp2f(acc[mi][ni][r]) : 0.0f;  // S already scaled by log2e/32
        Pb[(size_t)gi * WINDOW + gj] = f2bf(p);
        csum += p;
      }
    csum += __shfl_xor(csum, 16, 64);
    csum += __shfl_xor(csum, 32, 64);
    if ((lane >> 4) == 0) atomicAdd(&Db[gj], csum);
  }
}

// ---------------- Vdt[e][j] = V[j][e] / D[j]  (transpose + scale) ----------------
__global__ __launch_bounds__(256) void k_vdt(
    const u16* __restrict__ V, const float* __restrict__ D, u16* __restrict__ Vdt)
{
  __shared__ u16 tile[64][68];               // +4 pad keeps 8B alignment, breaks bank conflicts
  const int j0 = blockIdx.x * 64, e0 = blockIdx.y * 64, b = blockIdx.z;
  const u16* Vb = V   + (size_t)b * WINDOW * EMBED;
  u16* Tb       = Vdt + (size_t)b * EMBED * WINDOW;
  const float* Db = D + (size_t)b * WINDOW;
  const int t = threadIdx.x;
  const int rr = t >> 4;          // 0..15
  const int cc = (t & 15) * 4;    // 0..60
  #pragma unroll
  for (int p = 0; p < 4; ++p) {
    int r = p * 16 + rr;
    *(uint2*)&tile[r][cc] = *(const uint2*)(Vb + (size_t)(j0 + r) * EMBED + e0 + cc);
  }
  __syncthreads();
  #pragma unroll
  for (int p = 0; p < 4; ++p) {
    int er = p * 16 + rr;
    ushort4 o;
    o.x = f2bf(bf2f(tile[cc + 0][er]) / Db[j0 + cc + 0]);
    o.y = f2bf(bf2f(tile[cc + 1][er]) / Db[j0 + cc + 1]);
    o.z = f2bf(bf2f(tile[cc + 2][er]) / Db[j0 + cc + 2]);
    o.w = f2bf(bf2f(tile[cc + 3][er]) / Db[j0 + cc + 3]);
    *(ushort4*)(Tb + (size_t)(e0 + er) * WINDOW + j0 + cc) = o;
  }
}

// ---------------- O = P * Vdt^T  (causal K-length), fp32 out ----------------
__global__ __launch_bounds__(256) void k_out(
    const u16* __restrict__ P, const u16* __restrict__ Vdt, float* __restrict__ O)
{
  __shared__ u16 As[BM*BK], Bs[BN*BK];
  const int i0 = ((int)gridDim.x - 1 - (int)blockIdx.x) * BM;  // longest tiles first
  const int e0 = blockIdx.y * BN;
  const int b  = blockIdx.z;
  const u16* A = P   + (size_t)b * WINDOW * WINDOW + (size_t)i0 * WINDOW;
  const u16* B = Vdt + (size_t)b * EMBED * WINDOW  + (size_t)e0 * WINDOW;
  f32x4 acc[4][4]; zero_acc(acc);
  gemm_core(A, WINDOW, B, WINDOW, i0 + BM, As, Bs, acc);   // j <= i only

  float* Ob = O + (size_t)b * WINDOW * EMBED;
  const int lane = threadIdx.x & 63, w = threadIdx.x >> 6;
  const int wr = (w >> 1) * 64, wc = (w & 1) * 64;
  #pragma unroll
  for (int mi = 0; mi < 4; ++mi)
    #pragma unroll
    for (int ni = 0; ni < 4; ++ni)
      #pragma unroll
      for (int r = 0; r < 4; ++r) {
        int gi = i0 + wr + mi * 16 + (lane >> 4) * 4 + r;
        int ge = e0 + wc + ni * 16 + (lane & 15);
        Ob[(size_t)gi * EMBED + ge] = acc[mi][ni][r];
      }
}

extern "C" void kernel_launch(void* const* d_in, const int* in_sizes, int n_in,
                              void* d_out, int out_size, void* d_ws, size_t ws_size,
                              hipStream_t stream) {
  const float* X  = (const float*)d_in[0];
  const float* Wq = (const float*)d_in[1];
  const float* bq = (const float*)d_in[2];
  const float* Wk = (const float*)d_in[3];
  const float* bk = (const float*)d_in[4];
  const float* Wv = (const float*)d_in[5];
  const float* bv = (const float*)d_in[6];
  float* O = (float*)d_out;

  char* ws = (char*)d_ws;
  size_t off = 0;
  auto alloc = [&](size_t bytes) -> void* {
    void* p = ws + off; off += (bytes + 255) & ~(size_t)255; return p;
  };
  u16*  Xb  = (u16*)alloc((size_t)MTOT * EMBED * 2);          // 33.5 MB
  u16*  Wb  = (u16*)alloc((size_t)3 * EMBED * EMBED * 2);     //  6.3 MB
  u16*  Qb  = (u16*)alloc((size_t)MTOT * EMBED * 2);          // 33.5 MB
  u16*  Kb  = (u16*)alloc((size_t)MTOT * EMBED * 2);          // 33.5 MB (pre-scaled by log2e/32)
  u16*  Vb  = (u16*)alloc((size_t)MTOT * EMBED * 2);          // 33.5 MB
  u16*  Vdt = (u16*)alloc((size_t)BATCH * EMBED * WINDOW * 2);// 33.5 MB
  u16*  P   = (u16*)alloc((size_t)BATCH * WINDOW * WINDOW * 2);// 67.1 MB
  float* D  = (float*)alloc((size_t)MTOT * 4);                // 64 KB
  (void)ws_size; (void)in_sizes; (void)n_in; (void)out_size;

  // 0) fp32 -> bf16 converts
  k_cvt<<<dim3((MTOT * EMBED / 4 + 255) / 256), 256, 0, stream>>>(X, Xb, MTOT * EMBED);
  k_cvt<<<dim3((EMBED * EMBED / 4 + 255) / 256), 256, 0, stream>>>(Wq, Wb, EMBED * EMBED);
  k_cvt<<<dim3((EMBED * EMBED / 4 + 255) / 256), 256, 0, stream>>>(Wk, Wb + (size_t)EMBED * EMBED, EMBED * EMBED);
  k_cvt<<<dim3((EMBED * EMBED / 4 + 255) / 256), 256, 0, stream>>>(Wv, Wb + (size_t)2 * EMBED * EMBED, EMBED * EMBED);

  // 1) Q/K/V projections
  k_qkv<<<dim3(MTOT / BM, EMBED / BN, 3), 256, 0, stream>>>(Xb, Wb, bq, bk, bv, Qb, Kb, Vb);

  // 2) P = exp(QK^T/sqrt(E)) masked; D[j] = column sums (query-axis softmax denominator)
  (void)hipMemsetAsync(D, 0, (size_t)MTOT * 4, stream);
  k_spd<<<dim3(WINDOW / BM, WINDOW / BN, BATCH), 256, 0, stream>>>(Qb, Kb, P, D);

  // 3) Vdt[e][j] = V[j][e] / D[j]
  k_vdt<<<dim3(WINDOW / 64, EMBED / 64, BATCH), 256, 0, stream>>>(Vb, D, Vdt);

  // 4) O = P * Vdt^T (causal K-length per row-tile)
  k_out<<<dim3(WINDOW / BM, EMBED / BN, BATCH), 256, 0, stream>>>(P, Vdt, O);
}

// Round 2
// 341.444 us; speedup vs baseline: 1.1689x; 1.1689x over previous
//
#include <hip/hip_runtime.h>
#include <stdint.h>

#define WINDOW 2048
#define EMBED  1024
#define BATCH  8
#define MTOT   (BATCH*WINDOW)   // 16384 rows total

typedef unsigned short u16;
typedef __bf16 bf16x8 __attribute__((ext_vector_type(8)));
typedef float  f32x4  __attribute__((ext_vector_type(4)));

// ---- 256x128 tile, BK=64, 8 waves (4M x 2N -> 64x64 per wave), 3 LDS buffers ----
#define BM 256
#define BN 128
#define BK 64
#define ABUF (BM*BK)          // 16384 u16 = 32 KiB
#define BBUF (BN*BK)          //  8192 u16 = 16 KiB
#define BUFS (ABUF+BBUF)      // 24576 u16 = 48 KiB ; x3 buffers = 144 KiB LDS
#define KSCALE 0.04508422717564447f   /* log2(e)/32 folded into stored K */

#define WAITVM6 asm volatile("s_waitcnt vmcnt(6)" ::: "memory")
#define WAITVM0 asm volatile("s_waitcnt vmcnt(0)" ::: "memory")

__device__ __forceinline__ u16 f2bf(float f) {
  union { float f; unsigned u; } a; a.f = f;
  unsigned r = a.u + 0x7FFF + ((a.u >> 16) & 1);   // RNE
  return (u16)(r >> 16);
}
__device__ __forceinline__ float bf2f(u16 u) {
  union { unsigned u; float f; } a; a.u = ((unsigned)u) << 16;
  return a.f;
}

__device__ __forceinline__ void gload16(const u16* g, u16* l) {
  __builtin_amdgcn_global_load_lds(
      (const __attribute__((address_space(1))) unsigned int*)g,
      (__attribute__((address_space(3))) unsigned int*)l, 16, 0, 0);
}

// Stage one 16B chunk. LDS dest is LINEAR slot f=(row<<3)|cs; the global SOURCE
// column-chunk carries the inverse XOR swizzle (involution), so a reader at
// chunk (c ^ (row&7)) gets logical column-chunk c.  (rule #21: linear dest +
// inverse-swz source + swz on read)
__device__ __forceinline__ void stage_chunk(const u16* gt, int ld, u16* lb, int f) {
  int r = f >> 3, cs = f & 7;
  gload16(gt + (size_t)r * ld + (((cs ^ (r & 7)) << 3)), lb + f * 8);
}
// A-tile = 2048 chunks = 4 rounds of 512 threads; B-tile = 1024 chunks = 2 rounds.
__device__ __forceinline__ void stage_p0(const u16* At, int lda, u16* LA, int tid) {
  stage_chunk(At, lda, LA, 0*512 + tid);
  stage_chunk(At, lda, LA, 1*512 + tid);
  stage_chunk(At, lda, LA, 2*512 + tid);
}
__device__ __forceinline__ void stage_p1(const u16* At, int lda, const u16* Bt, int ldb,
                                         u16* LA, u16* LB, int tid) {
  stage_chunk(At, lda, LA, 3*512 + tid);
  stage_chunk(Bt, ldb, LB, 0*512 + tid);
  stage_chunk(Bt, ldb, LB, 1*512 + tid);
}

// acc[4][4] += A[256 x nt*64] * B[128 x nt*64]^T  (bf16 in, fp32 acc)
// 2-phase/K-tile schedule, counted vmcnt(6), raw s_barrier, setprio around MFMA.
__device__ __forceinline__ void gemm256_core(
    const u16* __restrict__ A, int lda,
    const u16* __restrict__ B, int ldb,
    int nt, u16* lds, f32x4 acc[4][4])
{
  const int tid  = threadIdx.x;
  const int lane = tid & 63;
  const int wid  = tid >> 6;
  const int wr   = (wid >> 1) * 64;   // wave M offset (0..192)
  const int wc   = (wid & 1) * 64;    // wave N offset (0/64)
  const int lrow = lane & 15;
  const int hi   = lane >> 4;         // 0..3
  const int sw   = lane & 7;          // == row&7 for all frag rows this lane reads

  // prologue: stage tiles 0 and 1 (12 loads/wave in flight)
  stage_p0(A, lda, lds, tid);
  stage_p1(A, lda, B, ldb, lds, lds + ABUF, tid);
  stage_p0(A + BK, lda, lds + BUFS, tid);
  stage_p1(A + BK, lda, B + BK, ldb, lds + BUFS, lds + BUFS + ABUF, tid);
  WAITVM6;                             // tile0 landed, tile1 in flight
  __builtin_amdgcn_s_barrier();

  for (int t = 0; t < nt; ++t) {
    u16* LA = lds + (t % 3) * BUFS;
    u16* LB = LA + ABUF;
    const bool s2 = (t + 2) < nt;
    const u16* A2 = A + (size_t)(t + 2) * BK;
    const u16* B2 = B + (size_t)(t + 2) * BK;
    u16* LA2 = lds + ((t + 2) % 3) * BUFS;
    u16* LB2 = LA2 + ABUF;

    bf16x8 av[4], bv[4];

    // ---------- phase 0 (kk=0) ----------
    if (s2) stage_p0(A2, lda, LA2, tid);
    {
      const int cA = hi ^ sw;                    // logical chunk kk*4+hi, swizzled
      #pragma unroll
      for (int mi = 0; mi < 4; ++mi)
        av[mi] = *(const bf16x8*)(LA + (wr + mi*16 + lrow) * 64 + cA * 8);
      #pragma unroll
      for (int ni = 0; ni < 4; ++ni)
        bv[ni] = *(const bf16x8*)(LB + (wc + ni*16 + lrow) * 64 + cA * 8);
    }
    __builtin_amdgcn_s_barrier();
    __builtin_amdgcn_s_setprio(1);
    #pragma unroll
    for (int mi = 0; mi < 4; ++mi)
      #pragma unroll
      for (int ni = 0; ni < 4; ++ni)
        acc[mi][ni] = __builtin_amdgcn_mfma_f32_16x16x32_bf16(av[mi], bv[ni], acc[mi][ni], 0, 0, 0);
    __builtin_amdgcn_s_setprio(0);
    __builtin_amdgcn_s_barrier();

    // ---------- phase 1 (kk=1) ----------
    if (s2) stage_p1(A2, lda, B2, ldb, LA2, LB2, tid);
    {
      const int cA = (4 + hi) ^ sw;
      #pragma unroll
      for (int mi = 0; mi < 4; ++mi)
        av[mi] = *(const bf16x8*)(LA + (wr + mi*16 + lrow) * 64 + cA * 8);
      #pragma unroll
      for (int ni = 0; ni < 4; ++ni)
        bv[ni] = *(const bf16x8*)(LB + (wc + ni*16 + lrow) * 64 + cA * 8);
    }
    __builtin_amdgcn_s_barrier();
    __builtin_amdgcn_s_setprio(1);
    #pragma unroll
    for (int mi = 0; mi < 4; ++mi)
      #pragma unroll
      for (int ni = 0; ni < 4; ++ni)
        acc[mi][ni] = __builtin_amdgcn_mfma_f32_16x16x32_bf16(av[mi], bv[ni], acc[mi][ni], 0, 0, 0);
    __builtin_amdgcn_s_setprio(0);
    // tile boundary: tile t+1 must be landed before next iteration reads it.
    // steady state keeps tile t+2's 6 loads in flight (never drain to 0 mid-loop).
    if (t + 1 < nt) { if (s2) { WAITVM6; } else { WAITVM0; } }
    __builtin_amdgcn_s_barrier();
  }
}

__device__ __forceinline__ void zero_acc(f32x4 acc[4][4]) {
  const f32x4 z = {0.f, 0.f, 0.f, 0.f};
  #pragma unroll
  for (int i = 0; i < 4; ++i)
    #pragma unroll
    for (int j = 0; j < 4; ++j) acc[i][j] = z;
}

// ---------------- fp32 -> bf16 convert (vectorized) ----------------
__global__ __launch_bounds__(256) void k_cvt(const float* __restrict__ in,
                                             u16* __restrict__ out, int n) {
  int i = (blockIdx.x * 256 + threadIdx.x) * 4;
  if (i >= n) return;
  float4 v = *(const float4*)(in + i);
  ushort4 o;
  o.x = f2bf(v.x); o.y = f2bf(v.y); o.z = f2bf(v.z); o.w = f2bf(v.w);
  *(ushort4*)(out + i) = o;
}

// ---------------- QKV projection: C = X * W^T + b ----------------
__global__ __launch_bounds__(512, 2) void k_qkv(
    const u16* __restrict__ Xb, const u16* __restrict__ Wb,
    const float* __restrict__ bq, const float* __restrict__ bk, const float* __restrict__ bv,
    u16* __restrict__ Q, u16* __restrict__ Ks, u16* __restrict__ V)
{
  __shared__ u16 lds[3 * BUFS];
  const int m0 = blockIdx.x * BM;
  const int n0 = blockIdx.y * BN;
  const int z  = blockIdx.z;
  const u16*   W    = Wb + (size_t)z * EMBED * EMBED;
  const float* bias = (z == 0) ? bq : (z == 1) ? bk : bv;
  u16* out          = (z == 0) ? Q  : (z == 1) ? Ks : V;
  const float scale = (z == 1) ? KSCALE : 1.0f;

  f32x4 acc[4][4]; zero_acc(acc);
  gemm256_core(Xb + (size_t)m0 * EMBED, EMBED, W + (size_t)n0 * EMBED, EMBED,
               EMBED / BK, lds, acc);

  const int lane = threadIdx.x & 63, wid = threadIdx.x >> 6;
  const int wr = (wid >> 1) * 64, wc = (wid & 1) * 64;
  #pragma unroll
  for (int mi = 0; mi < 4; ++mi)
    #pragma unroll
    for (int ni = 0; ni < 4; ++ni)
      #pragma unroll
      for (int rr = 0; rr < 4; ++rr) {
        int gm = m0 + wr + mi * 16 + (lane >> 4) * 4 + rr;
        int gn = n0 + wc + ni * 16 + (lane & 15);
        out[(size_t)gm * EMBED + gn] = f2bf((acc[mi][ni][rr] + bias[gn]) * scale);
      }
}

// ---------------- S = Q*K^T, P = exp2(S) masked, D[j] += colsum ----------------
__global__ __launch_bounds__(512, 2) void k_spd(
    const u16* __restrict__ Q, const u16* __restrict__ Ks,
    u16* __restrict__ P, float* __restrict__ D)
{
  const int i0 = blockIdx.x * BM;
  const int j0 = blockIdx.y * BN;
  if (j0 >= i0 + BM) return;                 // fully-masked tile: P never read there
  const int b  = blockIdx.z;
  __shared__ u16 lds[3 * BUFS];
  const u16* A = Q  + (size_t)b * WINDOW * EMBED + (size_t)i0 * EMBED;
  const u16* B = Ks + (size_t)b * WINDOW * EMBED + (size_t)j0 * EMBED;
  f32x4 acc[4][4]; zero_acc(acc);
  gemm256_core(A, EMBED, B, EMBED, EMBED / BK, lds, acc);

  u16* Pb   = P + (size_t)b * WINDOW * WINDOW;
  float* Db = D + (size_t)b * WINDOW;
  const int lane = threadIdx.x & 63, wid = threadIdx.x >> 6;
  const int wr = (wid >> 1) * 64, wc = (wid & 1) * 64;
  #pragma unroll
  for (int ni = 0; ni < 4; ++ni) {
    int gj = j0 + wc + ni * 16 + (lane & 15);
    float csum = 0.f;
    #pragma unroll
    for (int mi = 0; mi < 4; ++mi)
      #pragma unroll
      for (int rr = 0; rr < 4; ++rr) {
        int gi = i0 + wr + mi * 16 + (lane >> 4) * 4 + rr;
        float p = (gi >= gj) ? exp2f(acc[mi][ni][rr]) : 0.0f;  // S pre-scaled by log2e/32
        Pb[(size_t)gi * WINDOW + gj] = f2bf(p);
        csum += p;
      }
    csum += __shfl_xor(csum, 16, 64);
    csum += __shfl_xor(csum, 32, 64);
    if ((lane >> 4) == 0) atomicAdd(&Db[gj], csum);
  }
}

// ---------------- Vdt[e][j] = V[j][e] / D[j]  (transpose + scale) ----------------
__global__ __launch_bounds__(256) void k_vdt(
    const u16* __restrict__ V, const float* __restrict__ D, u16* __restrict__ Vdt)
{
  __shared__ u16 tile[64][68];
  const int j0 = blockIdx.x * 64, e0 = blockIdx.y * 64, b = blockIdx.z;
  const u16* Vb = V   + (size_t)b * WINDOW * EMBED;
  u16* Tb       = Vdt + (size_t)b * EMBED * WINDOW;
  const float* Db = D + (size_t)b * WINDOW;
  const int t = threadIdx.x;
  const int rr = t >> 4;
  const int cc = (t & 15) * 4;
  #pragma unroll
  for (int p = 0; p < 4; ++p) {
    int r = p * 16 + rr;
    *(uint2*)&tile[r][cc] = *(const uint2*)(Vb + (size_t)(j0 + r) * EMBED + e0 + cc);
  }
  __syncthreads();
  #pragma unroll
  for (int p = 0; p < 4; ++p) {
    int er = p * 16 + rr;
    ushort4 o;
    o.x = f2bf(bf2f(tile[cc + 0][er]) / Db[j0 + cc + 0]);
    o.y = f2bf(bf2f(tile[cc + 1][er]) / Db[j0 + cc + 1]);
    o.z = f2bf(bf2f(tile[cc + 2][er]) / Db[j0 + cc + 2]);
    o.w = f2bf(bf2f(tile[cc + 3][er]) / Db[j0 + cc + 3]);
    *(ushort4*)(Tb + (size_t)(e0 + er) * WINDOW + j0 + cc) = o;
  }
}

// ---------------- O = P * Vdt^T  (causal K-length), fp32 out ----------------
__global__ __launch_bounds__(512, 2) void k_out(
    const u16* __restrict__ P, const u16* __restrict__ Vdt, float* __restrict__ O)
{
  __shared__ u16 lds[3 * BUFS];
  const int i0 = ((int)gridDim.x - 1 - (int)blockIdx.x) * BM;  // longest first
  const int e0 = blockIdx.y * BN;
  const int b  = blockIdx.z;
  const u16* A = P   + (size_t)b * WINDOW * WINDOW + (size_t)i0 * WINDOW;
  const u16* B = Vdt + (size_t)b * EMBED * WINDOW  + (size_t)e0 * WINDOW;
  f32x4 acc[4][4]; zero_acc(acc);
  gemm256_core(A, WINDOW, B, WINDOW, (i0 + BM) / BK, lds, acc);  // j <= i only

  float* Ob = O + (size_t)b * WINDOW * EMBED;
  const int lane = threadIdx.x & 63, wid = threadIdx.x >> 6;
  const int wr = (wid >> 1) * 64, wc = (wid & 1) * 64;
  #pragma unroll
  for (int mi = 0; mi < 4; ++mi)
    #pragma unroll
    for (int ni = 0; ni < 4; ++ni)
      #pragma unroll
      for (int rr = 0; rr < 4; ++rr) {
        int gi = i0 + wr + mi * 16 + (lane >> 4) * 4 + rr;
        int ge = e0 + wc + ni * 16 + (lane & 15);
        Ob[(size_t)gi * EMBED + ge] = acc[mi][ni][rr];
      }
}

extern "C" void kernel_launch(void* const* d_in, const int* in_sizes, int n_in,
                              void* d_out, int out_size, void* d_ws, size_t ws_size,
                              hipStream_t stream) {
  const float* X  = (const float*)d_in[0];
  const float* Wq = (const float*)d_in[1];
  const float* bq = (const float*)d_in[2];
  const float* Wk = (const float*)d_in[3];
  const float* bk = (const float*)d_in[4];
  const float* Wv = (const float*)d_in[5];
  const float* bv = (const float*)d_in[6];
  float* O = (float*)d_out;

  char* ws = (char*)d_ws;
  size_t off = 0;
  auto alloc = [&](size_t bytes) -> void* {
    void* p = ws + off; off += (bytes + 255) & ~(size_t)255; return p;
  };
  u16*  Xb  = (u16*)alloc((size_t)MTOT * EMBED * 2);
  u16*  Wb  = (u16*)alloc((size_t)3 * EMBED * EMBED * 2);
  u16*  Qb  = (u16*)alloc((size_t)MTOT * EMBED * 2);
  u16*  Kb  = (u16*)alloc((size_t)MTOT * EMBED * 2);          // pre-scaled by log2e/32
  u16*  Vb  = (u16*)alloc((size_t)MTOT * EMBED * 2);
  u16*  Vdt = (u16*)alloc((size_t)BATCH * EMBED * WINDOW * 2);
  u16*  P   = (u16*)alloc((size_t)BATCH * WINDOW * WINDOW * 2);
  float* D  = (float*)alloc((size_t)MTOT * 4);
  (void)ws_size; (void)in_sizes; (void)n_in; (void)out_size;

  // 0) fp32 -> bf16 converts
  k_cvt<<<dim3((MTOT * EMBED / 4 + 255) / 256), 256, 0, stream>>>(X, Xb, MTOT * EMBED);
  k_cvt<<<dim3((EMBED * EMBED / 4 + 255) / 256), 256, 0, stream>>>(Wq, Wb, EMBED * EMBED);
  k_cvt<<<dim3((EMBED * EMBED / 4 + 255) / 256), 256, 0, stream>>>(Wk, Wb + (size_t)EMBED * EMBED, EMBED * EMBED);
  k_cvt<<<dim3((EMBED * EMBED / 4 + 255) / 256), 256, 0, stream>>>(Wv, Wb + (size_t)2 * EMBED * EMBED, EMBED * EMBED);

  // 1) Q/K/V projections
  k_qkv<<<dim3(MTOT / BM, EMBED / BN, 3), 512, 0, stream>>>(Xb, Wb, bq, bk, bv, Qb, Kb, Vb);

  // 2) P = exp(QK^T/sqrt(E)) masked; D[j] = column sums
  (void)hipMemsetAsync(D, 0, (size_t)MTOT * 4, stream);
  k_spd<<<dim3(WINDOW / BM, WINDOW / BN, BATCH), 512, 0, stream>>>(Qb, Kb, P, D);

  // 3) Vdt[e][j] = V[j][e] / D[j]
  k_vdt<<<dim3(WINDOW / 64, EMBED / 64, BATCH), 256, 0, stream>>>(Vb, D, Vdt);

  // 4) O = P * Vdt^T (causal K-length per row-tile)
  k_out<<<dim3(WINDOW / BM, EMBED / BN, BATCH), 512, 0, stream>>>(P, Vdt, O);
}

// Round 3
// 303.557 us; speedup vs baseline: 1.3148x; 1.1248x over previous
//
#include <hip/hip_runtime.h>
#include <stdint.h>

#define WINDOW 2048
#define EMBED  1024
#define BATCH  8
#define MTOT   (BATCH*WINDOW)   // 16384 rows total

typedef unsigned short u16;
typedef __bf16 bf16x8 __attribute__((ext_vector_type(8)));
typedef float  f32x4  __attribute__((ext_vector_type(4)));

// ---- m201 geometry: 256x256 tile, BK=64, 8 waves (2M x 4N -> 128x64/wave) ----
#define BM 256
#define BN 256
#define BK 64
#define HALF 8192   // u16 per kk-half: 256 rows x 32 cols  (16 KiB)
// LDS: A halves [buf][kk] then B halves [buf][kk] -> 8 * 16 KiB = 128 KiB
#define KSCALE 0.04508422717564447f   /* log2(e)/32 folded into stored K */

#define WAITVM4 asm volatile("s_waitcnt vmcnt(4)" ::: "memory")
#define WAITVM0 asm volatile("s_waitcnt vmcnt(0)" ::: "memory")

__device__ __forceinline__ u16 f2bf(float f) {
  union { float f; unsigned u; } a; a.f = f;
  unsigned r = a.u + 0x7FFF + ((a.u >> 16) & 1);   // RNE
  return (u16)(r >> 16);
}
__device__ __forceinline__ float bf2f(u16 u) {
  union { unsigned u; float f; } a; a.u = ((unsigned)u) << 16;
  return a.f;
}

__device__ __forceinline__ void gload16(const u16* g, u16* l) {
  __builtin_amdgcn_global_load_lds(
      (const __attribute__((address_space(1))) unsigned int*)g,
      (__attribute__((address_space(3))) unsigned int*)l, 16, 0, 0);
}

// Stage one kk-half (256 rows x 32 cols) of a tile into LDS.
// LDS dest is LINEAR slot f = r*4 + c (rule #21); the global SOURCE chunk is
// c ^ ((r>>1)&3) (involution), so reads at slot hi^((r>>1)&3) see logical
// chunk hi.  2-way bank aliasing on ds_read_b128 (free, m136).
__device__ __forceinline__ void stage_half(const u16* g, int ld, int kkc,
                                           u16* lb, int tid) {
  #pragma unroll
  for (int h = 0; h < 2; ++h) {
    int f = h * 512 + tid;
    int r = f >> 2, c = f & 3;
    gload16(g + (size_t)r * ld + kkc * 32 + ((c ^ ((r >> 1) & 3)) << 3),
            lb + f * 8);
  }
}

// acc[8][4] += A[256 x nt*64] * B[256 x nt*64]^T  (bf16 in, fp32 acc)
// 4 phases/K-tile, counted vmcnt(4), raw s_barrier, setprio around MFMA.
__device__ __forceinline__ void gemm256(
    const u16* __restrict__ A, int lda,
    const u16* __restrict__ B, int ldb,
    int nt, u16* lds, f32x4 acc[8][4])
{
  const int tid  = threadIdx.x;
  const int lane = tid & 63;
  const int wid  = tid >> 6;
  const int wm   = (wid >> 2) * 128;   // wave M offset (0/128)
  const int wn   = (wid & 3) * 64;     // wave N offset (0/64/128/192)
  const int lrow = lane & 15;
  const int hi   = lane >> 4;          // logical chunk 0..3
  u16* LDA = lds;                      // [buf*2+kk]*HALF
  u16* LDB = lds + 4 * HALF;

  // prologue: tile 0, kk0 halves first (needed at ph0), kk1 after
  stage_half(A, lda, 0, LDA + 0 * HALF, tid);
  stage_half(B, ldb, 0, LDB + 0 * HALF, tid);
  stage_half(A, lda, 1, LDA + 1 * HALF, tid);
  stage_half(B, ldb, 1, LDB + 1 * HALF, tid);
  WAITVM4;                              // kk0 halves landed, kk1 in flight
  __builtin_amdgcn_s_barrier();

  for (int t = 0; t < nt; ++t) {
    const int buf = (t & 1) * 2;
    const int nb  = ((t + 1) & 1) * 2;
    u16* LA0 = LDA + buf * HALF;
    u16* LA1 = LA0 + HALF;
    u16* LB0 = LDB + buf * HALF;
    u16* LB1 = LB0 + HALF;
    const bool s  = (t + 1) < nt;
    const u16* An = A + (size_t)(t + 1) * BK;
    const u16* Bn = B + (size_t)(t + 1) * BK;

    bf16x8 av[4], bv[4];

    // ---------- phase 0: (kk0, m-half 0) ----------
    #pragma unroll
    for (int mi = 0; mi < 4; ++mi) {
      int r = wm + mi * 16 + lrow;
      av[mi] = *(const bf16x8*)(LA0 + r * 32 + ((hi ^ ((r >> 1) & 3)) << 3));
    }
    #pragma unroll
    for (int ni = 0; ni < 4; ++ni) {
      int r = wn + ni * 16 + lrow;
      bv[ni] = *(const bf16x8*)(LB0 + r * 32 + ((hi ^ ((r >> 1) & 3)) << 3));
    }
    if (s) stage_half(An, lda, 0, LDA + nb * HALF, tid);
    __builtin_amdgcn_s_barrier();
    __builtin_amdgcn_s_setprio(1);
    #pragma unroll
    for (int mi = 0; mi < 4; ++mi)
      #pragma unroll
      for (int ni = 0; ni < 4; ++ni)
        acc[mi][ni] = __builtin_amdgcn_mfma_f32_16x16x32_bf16(av[mi], bv[ni], acc[mi][ni], 0, 0, 0);
    __builtin_amdgcn_s_setprio(0);
    __builtin_amdgcn_s_barrier();

    // ---------- phase 1: (kk0, m-half 1) — reuse bv ----------
    #pragma unroll
    for (int mi = 0; mi < 4; ++mi) {
      int r = wm + 64 + mi * 16 + lrow;
      av[mi] = *(const bf16x8*)(LA0 + r * 32 + ((hi ^ ((r >> 1) & 3)) << 3));
    }
    if (s) stage_half(Bn, ldb, 0, LDB + nb * HALF, tid);
    __builtin_amdgcn_s_barrier();
    __builtin_amdgcn_s_setprio(1);
    #pragma unroll
    for (int mi = 0; mi < 4; ++mi)
      #pragma unroll
      for (int ni = 0; ni < 4; ++ni)
        acc[4 + mi][ni] = __builtin_amdgcn_mfma_f32_16x16x32_bf16(av[mi], bv[ni], acc[4 + mi][ni], 0, 0, 0);
    __builtin_amdgcn_s_setprio(0);
    // current tile's kk1 halves must be landed before ph2 reads them.
    if (s) { WAITVM4; } else { WAITVM0; }
    __builtin_amdgcn_s_barrier();

    // ---------- phase 2: (kk1, m-half 0) ----------
    #pragma unroll
    for (int mi = 0; mi < 4; ++mi) {
      int r = wm + mi * 16 + lrow;
      av[mi] = *(const bf16x8*)(LA1 + r * 32 + ((hi ^ ((r >> 1) & 3)) << 3));
    }
    #pragma unroll
    for (int ni = 0; ni < 4; ++ni) {
      int r = wn + ni * 16 + lrow;
      bv[ni] = *(const bf16x8*)(LB1 + r * 32 + ((hi ^ ((r >> 1) & 3)) << 3));
    }
    if (s) stage_half(An, lda, 1, LDA + nb * HALF + HALF, tid);
    __builtin_amdgcn_s_barrier();
    __builtin_amdgcn_s_setprio(1);
    #pragma unroll
    for (int mi = 0; mi < 4; ++mi)
      #pragma unroll
      for (int ni = 0; ni < 4; ++ni)
        acc[mi][ni] = __builtin_amdgcn_mfma_f32_16x16x32_bf16(av[mi], bv[ni], acc[mi][ni], 0, 0, 0);
    __builtin_amdgcn_s_setprio(0);
    __builtin_amdgcn_s_barrier();

    // ---------- phase 3: (kk1, m-half 1) — reuse bv ----------
    #pragma unroll
    for (int mi = 0; mi < 4; ++mi) {
      int r = wm + 64 + mi * 16 + lrow;
      av[mi] = *(const bf16x8*)(LA1 + r * 32 + ((hi ^ ((r >> 1) & 3)) << 3));
    }
    if (s) stage_half(Bn, ldb, 1, LDB + nb * HALF + HALF, tid);
    __builtin_amdgcn_s_barrier();
    __builtin_amdgcn_s_setprio(1);
    #pragma unroll
    for (int mi = 0; mi < 4; ++mi)
      #pragma unroll
      for (int ni = 0; ni < 4; ++ni)
        acc[4 + mi][ni] = __builtin_amdgcn_mfma_f32_16x16x32_bf16(av[mi], bv[ni], acc[4 + mi][ni], 0, 0, 0);
    __builtin_amdgcn_s_setprio(0);
    // next tile's kk0 halves must be landed before next iteration's ph0.
    if (s) { WAITVM4; }
    __builtin_amdgcn_s_barrier();
  }
}

__device__ __forceinline__ void zero_acc(f32x4 acc[8][4]) {
  const f32x4 z = {0.f, 0.f, 0.f, 0.f};
  #pragma unroll
  for (int i = 0; i < 8; ++i)
    #pragma unroll
    for (int j = 0; j < 4; ++j) acc[i][j] = z;
}

// ---------------- fp32 -> bf16 convert (vectorized) ----------------
__global__ __launch_bounds__(256) void k_cvt(const float* __restrict__ in,
                                             u16* __restrict__ out, int n) {
  int i = (blockIdx.x * 256 + threadIdx.x) * 4;
  if (i >= n) return;
  float4 v = *(const float4*)(in + i);
  ushort4 o;
  o.x = f2bf(v.x); o.y = f2bf(v.y); o.z = f2bf(v.z); o.w = f2bf(v.w);
  *(ushort4*)(out + i) = o;
}

// ---------------- QKV projection: C = X * W^T + b ----------------
__global__ __launch_bounds__(512, 2) void k_qkv(
    const u16* __restrict__ Xb, const u16* __restrict__ Wb,
    const float* __restrict__ bq, const float* __restrict__ bk, const float* __restrict__ bv,
    u16* __restrict__ Q, u16* __restrict__ Ks, u16* __restrict__ V)
{
  __shared__ u16 lds[8 * HALF];
  const int m0 = blockIdx.x * BM;
  const int n0 = blockIdx.y * BN;
  const int z  = blockIdx.z;
  const u16*   W    = Wb + (size_t)z * EMBED * EMBED;
  const float* bias = (z == 0) ? bq : (z == 1) ? bk : bv;
  u16* out          = (z == 0) ? Q  : (z == 1) ? Ks : V;
  const float scale = (z == 1) ? KSCALE : 1.0f;

  f32x4 acc[8][4]; zero_acc(acc);
  gemm256(Xb + (size_t)m0 * EMBED, EMBED, W + (size_t)n0 * EMBED, EMBED,
          EMBED / BK, lds, acc);

  const int lane = threadIdx.x & 63, wid = threadIdx.x >> 6;
  const int wm = (wid >> 2) * 128, wn = (wid & 3) * 64;
  const int lrow = lane & 15, hi = lane >> 4;
  #pragma unroll
  for (int mi = 0; mi < 8; ++mi)
    #pragma unroll
    for (int ni = 0; ni < 4; ++ni)
      #pragma unroll
      for (int rr = 0; rr < 4; ++rr) {
        int gm = m0 + wm + mi * 16 + hi * 4 + rr;
        int gn = n0 + wn + ni * 16 + lrow;
        out[(size_t)gm * EMBED + gn] = f2bf((acc[mi][ni][rr] + bias[gn]) * scale);
      }
}

// ---------------- S = Q*K^T, P = exp2(S) masked, D[j] += colsum ----------------
__global__ __launch_bounds__(512, 2) void k_spd(
    const u16* __restrict__ Q, const u16* __restrict__ Ks,
    u16* __restrict__ P, float* __restrict__ D)
{
  const int i0 = blockIdx.x * BM;
  const int j0 = blockIdx.y * BN;
  if (j0 > i0) return;                       // fully-masked tile: P never read there
  const int b  = blockIdx.z;
  __shared__ u16 lds[8 * HALF];
  const u16* A = Q  + (size_t)b * WINDOW * EMBED + (size_t)i0 * EMBED;
  const u16* B = Ks + (size_t)b * WINDOW * EMBED + (size_t)j0 * EMBED;
  f32x4 acc[8][4]; zero_acc(acc);
  gemm256(A, EMBED, B, EMBED, EMBED / BK, lds, acc);

  u16* Pb   = P + (size_t)b * WINDOW * WINDOW;
  float* Db = D + (size_t)b * WINDOW;
  const int lane = threadIdx.x & 63, wid = threadIdx.x >> 6;
  const int wm = (wid >> 2) * 128, wn = (wid & 3) * 64;
  const int lrow = lane & 15, hi = lane >> 4;
  #pragma unroll
  for (int ni = 0; ni < 4; ++ni) {
    int gj = j0 + wn + ni * 16 + lrow;
    float csum = 0.f;
    #pragma unroll
    for (int mi = 0; mi < 8; ++mi)
      #pragma unroll
      for (int rr = 0; rr < 4; ++rr) {
        int gi = i0 + wm + mi * 16 + hi * 4 + rr;
        float p = (gi >= gj) ? exp2f(acc[mi][ni][rr]) : 0.0f;  // S pre-scaled by log2e/32
        Pb[(size_t)gi * WINDOW + gj] = f2bf(p);
        csum += p;
      }
    csum += __shfl_xor(csum, 16, 64);
    csum += __shfl_xor(csum, 32, 64);
    if (hi == 0) atomicAdd(&Db[gj], csum);
  }
}

// ---------------- Vdt[e][j] = V[j][e] / D[j]  (transpose + scale) ----------------
__global__ __launch_bounds__(256) void k_vdt(
    const u16* __restrict__ V, const float* __restrict__ D, u16* __restrict__ Vdt)
{
  __shared__ u16 tile[64][68];
  const int j0 = blockIdx.x * 64, e0 = blockIdx.y * 64, b = blockIdx.z;
  const u16* Vb = V   + (size_t)b * WINDOW * EMBED;
  u16* Tb       = Vdt + (size_t)b * EMBED * WINDOW;
  const float* Db = D + (size_t)b * WINDOW;
  const int t = threadIdx.x;
  const int rr = t >> 4;
  const int cc = (t & 15) * 4;
  #pragma unroll
  for (int p = 0; p < 4; ++p) {
    int r = p * 16 + rr;
    *(uint2*)&tile[r][cc] = *(const uint2*)(Vb + (size_t)(j0 + r) * EMBED + e0 + cc);
  }
  __syncthreads();
  #pragma unroll
  for (int p = 0; p < 4; ++p) {
    int er = p * 16 + rr;
    ushort4 o;
    o.x = f2bf(bf2f(tile[cc + 0][er]) / Db[j0 + cc + 0]);
    o.y = f2bf(bf2f(tile[cc + 1][er]) / Db[j0 + cc + 1]);
    o.z = f2bf(bf2f(tile[cc + 2][er]) / Db[j0 + cc + 2]);
    o.w = f2bf(bf2f(tile[cc + 3][er]) / Db[j0 + cc + 3]);
    *(ushort4*)(Tb + (size_t)(e0 + er) * WINDOW + j0 + cc) = o;
  }
}

// ---------------- O = P * Vdt^T  (causal K-length), fp32 out ----------------
__global__ __launch_bounds__(512, 2) void k_out(
    const u16* __restrict__ P, const u16* __restrict__ Vdt, float* __restrict__ O)
{
  __shared__ u16 lds[8 * HALF];
  const int i0 = ((int)gridDim.x - 1 - (int)blockIdx.x) * BM;  // longest first
  const int e0 = blockIdx.y * BN;
  const int b  = blockIdx.z;
  const u16* A = P   + (size_t)b * WINDOW * WINDOW + (size_t)i0 * WINDOW;
  const u16* B = Vdt + (size_t)b * EMBED * WINDOW  + (size_t)e0 * WINDOW;
  f32x4 acc[8][4]; zero_acc(acc);
  gemm256(A, WINDOW, B, WINDOW, (i0 + BM) / BK, lds, acc);  // j <= i only

  float* Ob = O + (size_t)b * WINDOW * EMBED;
  const int lane = threadIdx.x & 63, wid = threadIdx.x >> 6;
  const int wm = (wid >> 2) * 128, wn = (wid & 3) * 64;
  const int lrow = lane & 15, hi = lane >> 4;
  #pragma unroll
  for (int mi = 0; mi < 8; ++mi)
    #pragma unroll
    for (int ni = 0; ni < 4; ++ni)
      #pragma unroll
      for (int rr = 0; rr < 4; ++rr) {
        int gi = i0 + wm + mi * 16 + hi * 4 + rr;
        int ge = e0 + wn + ni * 16 + lrow;
        Ob[(size_t)gi * EMBED + ge] = acc[mi][ni][rr];
      }
}

extern "C" void kernel_launch(void* const* d_in, const int* in_sizes, int n_in,
                              void* d_out, int out_size, void* d_ws, size_t ws_size,
                              hipStream_t stream) {
  const float* X  = (const float*)d_in[0];
  const float* Wq = (const float*)d_in[1];
  const float* bq = (const float*)d_in[2];
  const float* Wk = (const float*)d_in[3];
  const float* bk = (const float*)d_in[4];
  const float* Wv = (const float*)d_in[5];
  const float* bv = (const float*)d_in[6];
  float* O = (float*)d_out;

  char* ws = (char*)d_ws;
  size_t off = 0;
  auto alloc = [&](size_t bytes) -> void* {
    void* p = ws + off; off += (bytes + 255) & ~(size_t)255; return p;
  };
  u16*  Xb  = (u16*)alloc((size_t)MTOT * EMBED * 2);
  u16*  Wb  = (u16*)alloc((size_t)3 * EMBED * EMBED * 2);
  u16*  Qb  = (u16*)alloc((size_t)MTOT * EMBED * 2);
  u16*  Kb  = (u16*)alloc((size_t)MTOT * EMBED * 2);          // pre-scaled by log2e/32
  u16*  Vb  = (u16*)alloc((size_t)MTOT * EMBED * 2);
  u16*  Vdt = (u16*)alloc((size_t)BATCH * EMBED * WINDOW * 2);
  u16*  P   = (u16*)alloc((size_t)BATCH * WINDOW * WINDOW * 2);
  float* D  = (float*)alloc((size_t)MTOT * 4);
  (void)ws_size; (void)in_sizes; (void)n_in; (void)out_size;

  // 0) fp32 -> bf16 converts
  k_cvt<<<dim3((MTOT * EMBED / 4 + 255) / 256), 256, 0, stream>>>(X, Xb, MTOT * EMBED);
  k_cvt<<<dim3((EMBED * EMBED / 4 + 255) / 256), 256, 0, stream>>>(Wq, Wb, EMBED * EMBED);
  k_cvt<<<dim3((EMBED * EMBED / 4 + 255) / 256), 256, 0, stream>>>(Wk, Wb + (size_t)EMBED * EMBED, EMBED * EMBED);
  k_cvt<<<dim3((EMBED * EMBED / 4 + 255) / 256), 256, 0, stream>>>(Wv, Wb + (size_t)2 * EMBED * EMBED, EMBED * EMBED);

  // 1) Q/K/V projections
  k_qkv<<<dim3(MTOT / BM, EMBED / BN, 3), 512, 0, stream>>>(Xb, Wb, bq, bk, bv, Qb, Kb, Vb);

  // 2) P = exp(QK^T/sqrt(E)) masked; D[j] = column sums
  (void)hipMemsetAsync(D, 0, (size_t)MTOT * 4, stream);
  k_spd<<<dim3(WINDOW / BM, WINDOW / BN, BATCH), 512, 0, stream>>>(Qb, Kb, P, D);

  // 3) Vdt[e][j] = V[j][e] / D[j]
  k_vdt<<<dim3(WINDOW / 64, EMBED / 64, BATCH), 256, 0, stream>>>(Vb, D, Vdt);

  // 4) O = P * Vdt^T (causal K-length per row-tile)
  k_out<<<dim3(WINDOW / BM, EMBED / BN, BATCH), 512, 0, stream>>>(P, Vdt, O);
}